// Round 9
// baseline (244.303 us; speedup 1.0000x reference)
//
#include <hip/hip_runtime.h>

typedef short bf16x8 __attribute__((ext_vector_type(8)));
typedef float f32x4 __attribute__((ext_vector_type(4)));

// Problem constants (fixed by reference setup_inputs)
constexpr int Bc = 4;
constexpr int Nc = 50000;
constexpr int Kc = 10;
constexpr int Fc = 128;
constexpr int Hc = 16;
constexpr int Cc = 64;            // 4*H output channels
constexpr int NODES = Bc * Nc;    // 200000
constexpr int NPB = 8;            // nodes per tile
constexpr int ROWS = NPB * Kc;    // 80 GEMM rows per tile
constexpr int MT = ROWS / 16;     // 5 M-tiles
constexpr int BLK = 256;          // 4 waves
constexpr int NTILES = NODES / NPB;  // 25000
constexpr int GRID = 512;            // persistent: exactly 2 blocks/CU

// LDS: two x buffers, fp32 [80 rows][512 B], 16B-unit XOR-swizzled via SOURCE addr.
// 2 x 40960 = 81920 B -> 2 blocks/CU (2 x 81920 = 163840 = full LDS).
// hw f32 [80][68] + ol f32 [8][68] alias the JUST-CONSUMED buffer (disjoint
// from the buffer receiving the in-flight DMA).
constexpr int BUF_BYTES = ROWS * Fc * 4;   // 40960
constexpr int LDS_BYTES = 2 * BUF_BYTES;   // 81920
constexpr int OL_OFF = 21760;              // hw ends at 80*68*4 = 21760

__device__ __forceinline__ unsigned short f2bf(float f) {
    // round-to-nearest-even fp32 -> bf16 (prep kernel only)
    unsigned u = __builtin_bit_cast(unsigned, f);
    return (unsigned short)((u + 0x7fffu + ((u >> 16) & 1u)) >> 16);
}

__device__ __forceinline__ unsigned cvtpk(float lo, float hi) {
    // packed RNE fp32->bf16: D[15:0]=bf16(lo), D[31:16]=bf16(hi)
    unsigned r;
    asm("v_cvt_pk_bf16_f32 %0, %1, %2" : "=v"(r) : "v"(lo), "v"(hi));
    return r;
}

// raw barrier: order LDS only; NEVER drains vmcnt -> DMA stays in flight.
__device__ __forceinline__ void barrier_lds() {
    asm volatile("s_waitcnt lgkmcnt(0)" ::: "memory");
    __builtin_amdgcn_sched_barrier(0);
    __builtin_amdgcn_s_barrier();
    __builtin_amdgcn_sched_barrier(0);
}

// Prep: W [128][64] f32 -> per-lane B-fragment image in d_ws (bf16).
// dst = w*2048 + l*32 + kc*8 + j  <->  c = w*16 + (l&15), f = kc*32 + (l>>4)*8 + j.
__global__ __launch_bounds__(256)
void prep_w(const float* __restrict__ W, unsigned short* __restrict__ wt) {
    const int dst = blockIdx.x * 256 + threadIdx.x;   // 8192 total
    const int j  = dst & 7;
    const int kc = (dst >> 3) & 3;
    const int l  = (dst >> 5) & 63;
    const int w  = dst >> 11;
    const int c  = w * 16 + (l & 15);
    const int f  = kc * 32 + (l >> 4) * 8 + j;
    wt[dst] = f2bf(W[f * 64 + c]);
}

__global__ __launch_bounds__(BLK, 2)
void gat_kernel(const float* __restrict__ x,
                const unsigned short* __restrict__ wt_ws,
                const float* __restrict__ a,
                float* __restrict__ out)
{
    __shared__ __align__(16) char smem[LDS_BYTES];

    const int t  = threadIdx.x;
    const int w  = t >> 6;    // wave -> col-tile
    const int l  = t & 63;
    const int lr = l & 15;    // A-row / B-col within tile
    const int lk = l >> 4;    // k sub-block (8 contiguous k)
    const int h  = t & 15;

    // hoisted loads (oldest in vmcnt order; retired long before steady state)
    bf16x8 bfrag[4];
    {
        const bf16x8* wp = reinterpret_cast<const bf16x8*>(wt_ws + w * 2048 + l * 32);
#pragma unroll
        for (int kc = 0; kc < 4; ++kc) bfrag[kc] = wp[kc];
    }
    const float ar0 = a[h];
    const float ar1 = a[16 + h];
    const float ar2 = a[32 + h];
    const float ar3 = a[48 + h];

    // DMA geometry: wave w, lane l covers row j*8 + w*2 + (l>>5); 16B source unit
    // (l&31)^(row&7) lands at linear LDS slot (l&31)  => slot u holds global unit
    // u^(row&7); read side XORs the same (rule 21: inverse-swz source + swz read).
    const int rsub = w * 2 + (l >> 5);                 // == row & 7 for every j
    const int unit = (l & 31) ^ rsub;
    const size_t lane_goff = (size_t)rsub * 512 + (size_t)unit * 16;

    int tile = blockIdx.x;
    // ---- prologue: DMA tile -> buf 0 ----
    {
        const char* gsrc = reinterpret_cast<const char*>(x) + (size_t)tile * BUF_BYTES + lane_goff;
#pragma unroll
        for (int j = 0; j < 10; ++j)
            __builtin_amdgcn_global_load_lds(
                (const __attribute__((address_space(1))) void*)(gsrc + j * 4096),
                (__attribute__((address_space(3))) void*)(smem + j * 4096 + w * 1024),
                16, 0, 0);
    }
    int p = 0;

    for (;;) {
        char* Abuf = smem + p * BUF_BYTES;
        char* Bbuf = smem + (p ^ 1) * BUF_BYTES;
        const int ntile = tile + GRID;

        // ---- (a) prefetch tile i+1 into B; (b) counted wait for tile i ----
        if (ntile < NTILES) {
            const char* gsrc = reinterpret_cast<const char*>(x) + (size_t)ntile * BUF_BYTES + lane_goff;
#pragma unroll
            for (int j = 0; j < 10; ++j)
                __builtin_amdgcn_global_load_lds(
                    (const __attribute__((address_space(1))) void*)(gsrc + j * 4096),
                    (__attribute__((address_space(3))) void*)(Bbuf + j * 4096 + w * 1024),
                    16, 0, 0);
            // newest 10 = tile i+1's loads; vmcnt returns in issue order, so
            // <=10 outstanding  =>  all of tile i's loads have landed.
            asm volatile("s_waitcnt vmcnt(10)" ::: "memory");
        } else {
            asm volatile("s_waitcnt vmcnt(0)" ::: "memory");
        }
        __builtin_amdgcn_sched_barrier(0);
        __builtin_amdgcn_s_barrier();
        __builtin_amdgcn_sched_barrier(0);

        // ---- (c) MFMA  hw[80][64] = bf16(x_tile) . Wt^T, cvt in-regs ----
        f32x4 acc[MT];
#pragma unroll
        for (int m = 0; m < MT; ++m) acc[m] = (f32x4){0.f, 0.f, 0.f, 0.f};
        const int rsw = lr & 7;
#pragma unroll
        for (int m = 0; m < MT; ++m) {
            const char* xrow = Abuf + (m * 16 + lr) * 512;
#pragma unroll
            for (int kc = 0; kc < 4; ++kc) {
                const int u0 = kc * 8 + lk * 2;
                const f32x4 p0 = *reinterpret_cast<const f32x4*>(xrow + ((u0)     ^ rsw) * 16);
                const f32x4 p1 = *reinterpret_cast<const f32x4*>(xrow + ((u0 + 1) ^ rsw) * 16);
                union { unsigned u[4]; bf16x8 v; } af;
                af.u[0] = cvtpk(p0[0], p0[1]);
                af.u[1] = cvtpk(p0[2], p0[3]);
                af.u[2] = cvtpk(p1[0], p1[1]);
                af.u[3] = cvtpk(p1[2], p1[3]);
                acc[m] = __builtin_amdgcn_mfma_f32_16x16x32_bf16(af.v, bfrag[kc], acc[m], 0, 0, 0);
            }
        }
        barrier_lds();   // (d) all waves' reads of Abuf done -> may overwrite with hw

        // ---- (e1) acc -> hw f32 [80][68] in Abuf (D-frag: row = lk*4+r, col = lr) ----
        {
            float* hw = reinterpret_cast<float*>(Abuf);
            const int col = w * 16 + lr;
#pragma unroll
            for (int m = 0; m < MT; ++m) {
                const int rbase = m * 16 + lk * 4;
#pragma unroll
                for (int r = 0; r < 4; ++r)
                    hw[(rbase + r) * 68 + col] = acc[m][r];
            }
        }
        barrier_lds();

        // ---- (e2) online softmax over K=10 + leaky relu, thread = (node, head) ----
        if (t < NPB * Hc) {   // 128 active
            const int ln = t >> 4;
            const float* hwb = reinterpret_cast<const float*>(Abuf) + (ln * Kc) * 68 + h * 4;
            float mx = -1e30f, lsum = 0.f;
            float o0 = 0.f, o1 = 0.f, o2 = 0.f, o3 = 0.f;
#pragma unroll
            for (int k = 0; k < Kc; ++k) {
                const float4 hv = *reinterpret_cast<const float4*>(hwb + k * 68);
                const float lg = fmaf(hv.x, ar0, fmaf(hv.y, ar1, fmaf(hv.z, ar2, hv.w * ar3)));
                const float mn = fmaxf(mx, lg);
                const float s  = __expf(mx - mn);
                const float pp = __expf(lg - mn);
                mx = mn;
                lsum = fmaf(lsum, s, pp);
                o0 = fmaf(o0, s, pp * hv.x);
                o1 = fmaf(o1, s, pp * hv.y);
                o2 = fmaf(o2, s, pp * hv.z);
                o3 = fmaf(o3, s, pp * hv.w);
            }
            const float inv = 1.f / lsum;
            o0 *= inv; o1 *= inv; o2 *= inv; o3 *= inv;
            o0 = fmaxf(o0, 0.2f * o0);   // leaky_relu slope 0.2
            o1 = fmaxf(o1, 0.2f * o1);
            o2 = fmaxf(o2, 0.2f * o2);
            o3 = fmaxf(o3, 0.2f * o3);
            float* ol = reinterpret_cast<float*>(Abuf + OL_OFF);
            *reinterpret_cast<float4*>(ol + ln * 68 + h * 4) = make_float4(o0, o1, o2, o3);
        }
        barrier_lds();

        // ---- (e3) store transposed [B, 64, N], coalesced float4 ----
        if (t < 128) {
            const float* ol = reinterpret_cast<const float*>(Abuf + OL_OFF);
            const int c  = t >> 1;   // channel 0..63
            const int nq = t & 1;    // node quad 0..1
            const int nb = tile * NPB;
            const int b  = nb / Nc;
            const int n0 = nb - b * Nc;
            float4 v;
            v.x = ol[(nq * 4 + 0) * 68 + c];
            v.y = ol[(nq * 4 + 1) * 68 + c];
            v.z = ol[(nq * 4 + 2) * 68 + c];
            v.w = ol[(nq * 4 + 3) * 68 + c];
            *reinterpret_cast<float4*>(out + ((size_t)b * Cc + c) * Nc + n0 + nq * 4) = v;
        }
        // loop-bottom barrier: all ol reads done before next iter's DMA targets Abuf
        barrier_lds();

        tile = ntile;
        p ^= 1;
        if (tile >= NTILES) break;
    }
}

extern "C" void kernel_launch(void* const* d_in, const int* in_sizes, int n_in,
                              void* d_out, int out_size, void* d_ws, size_t ws_size,
                              hipStream_t stream) {
    const float* x = (const float*)d_in[0];
    const float* W = (const float*)d_in[1];
    const float* a = (const float*)d_in[2];
    float* out = (float*)d_out;
    unsigned short* wt = (unsigned short*)d_ws;   // 16 KB used

    prep_w<<<32, 256, 0, stream>>>(W, wt);
    gat_kernel<<<GRID, BLK, 0, stream>>>(x, wt, a, out);
}

// Round 10
// 242.138 us; speedup vs baseline: 1.0089x; 1.0089x over previous
//
#include <hip/hip_runtime.h>

typedef short bf16x8 __attribute__((ext_vector_type(8)));
typedef float f32x4 __attribute__((ext_vector_type(4)));

// Problem constants (fixed by reference setup_inputs)
constexpr int Bc = 4;
constexpr int Nc = 50000;
constexpr int Kc = 10;
constexpr int Fc = 128;
constexpr int Hc = 16;
constexpr int Cc = 64;            // 4*H output channels
constexpr int NODES = Bc * Nc;    // 200000
constexpr int NPB = 8;            // nodes per block
constexpr int ROWS = NPB * Kc;    // 80 GEMM rows per block
constexpr int BLK = 256;          // 4 waves, M-split: wave w owns m-tile w (wave 3: m=3,4)
constexpr int NTILES = NODES / NPB;  // 25000

// LDS: x fp32 [80 rows][512 B], 16B-unit XOR-swizzled via SOURCE addr = 40960 B
//   -> 4 blocks/CU. After the compute barrier the x region is aliased by:
//   hw f32 [80][68]  bytes [0, 21760) ; ol f32 [8][68] bytes [21760, 23936)
constexpr int BUF_BYTES = ROWS * Fc * 4;   // 40960
constexpr int OL_OFF = 21760;

__device__ __forceinline__ unsigned short f2bf(float f) {
    // round-to-nearest-even fp32 -> bf16 (prep kernel only)
    unsigned u = __builtin_bit_cast(unsigned, f);
    return (unsigned short)((u + 0x7fffu + ((u >> 16) & 1u)) >> 16);
}

__device__ __forceinline__ unsigned cvtpk(float lo, float hi) {
    // packed RNE fp32->bf16: D[15:0]=bf16(lo), D[31:16]=bf16(hi)
    unsigned r;
    asm("v_cvt_pk_bf16_f32 %0, %1, %2" : "=v"(r) : "v"(lo), "v"(hi));
    return r;
}

// raw barrier: order LDS only (never drains vmcnt)
__device__ __forceinline__ void barrier_lds() {
    asm volatile("s_waitcnt lgkmcnt(0)" ::: "memory");
    __builtin_amdgcn_sched_barrier(0);
    __builtin_amdgcn_s_barrier();
    __builtin_amdgcn_sched_barrier(0);
}

// Prep: W [128][64] f32 -> per-lane B-fragment image in d_ws (bf16).
// dst = n*2048 + l*32 + kc*8 + j  <->  c = n*16 + (l&15), f = kc*32 + (l>>4)*8 + j.
__global__ __launch_bounds__(256)
void prep_w(const float* __restrict__ W, unsigned short* __restrict__ wt) {
    const int dst = blockIdx.x * 256 + threadIdx.x;   // 8192 total
    const int j  = dst & 7;
    const int kc = (dst >> 3) & 3;
    const int l  = (dst >> 5) & 63;
    const int n  = dst >> 11;
    const int c  = n * 16 + (l & 15);
    const int f  = kc * 32 + (l >> 4) * 8 + j;
    wt[dst] = f2bf(W[f * 64 + c]);
}

__global__ __launch_bounds__(BLK, 4)
void gat_kernel(const float* __restrict__ x,
                const unsigned short* __restrict__ wt_ws,
                const float* __restrict__ a,
                float* __restrict__ out)
{
    __shared__ __align__(16) char smem[BUF_BYTES];

    const int t   = threadIdx.x;
    const int w   = t >> 6;    // wave -> m-tile owner (wave 3 owns m=3 and m=4)
    const int l   = t & 63;
    const int lr  = l & 15;    // A-row within m-tile / hw col-low
    const int lk  = l >> 4;    // k sub-block (8 contiguous k) / D-frag row group
    const int l5  = l >> 5;
    const int l31 = l & 31;

    // ---- B fragments: ALL 4 col-tiles per wave (wt image is L1-resident) ----
    bf16x8 bfrag[4][4];   // [n][kc]
#pragma unroll
    for (int n = 0; n < 4; ++n) {
        const bf16x8* wp = reinterpret_cast<const bf16x8*>(wt_ws + n * 2048 + l * 32);
#pragma unroll
        for (int kc = 0; kc < 4; ++kc) bfrag[n][kc] = wp[kc];
    }
    // drain bfrag so subsequent hand-counted vmcnt sees only DMA loads
    asm volatile("s_waitcnt vmcnt(0)" ::: "memory");
    __builtin_amdgcn_sched_barrier(0);

    // ---- DMA: wave w issues ONLY its own m-tile rows (wave-private pipeline) ----
    // instr j of m-tile m covers rows m*16 + 2j + (l>>5); 16B source unit
    // (l&31)^(row&7); LDS dest uniform base m*8192 + j*1024, lane auto +l*16
    // => LDS slot u of row r holds global unit u^(r&7); read XORs the same.
    const char* xt = reinterpret_cast<const char*>(x) + (size_t)blockIdx.x * BUF_BYTES;

    auto issue_m = [&](int m) {
#pragma unroll
        for (int j = 0; j < 8; ++j) {
            const int rl   = 2 * j + l5;
            const int unit = l31 ^ (rl & 7);
            __builtin_amdgcn_global_load_lds(
                (const __attribute__((address_space(1))) void*)(xt + (size_t)(m * 16 + rl) * 512 + unit * 16),
                (__attribute__((address_space(3))) void*)(smem + m * 8192 + j * 1024),
                16, 0, 0);
        }
    };

    issue_m(w);
    if (w == 3) {
        issue_m(4);
        asm volatile("s_waitcnt vmcnt(8)" ::: "memory");   // m=3's 8 loads landed
    } else {
        asm volatile("s_waitcnt vmcnt(0)" ::: "memory");   // my 8 loads landed
    }
    __builtin_amdgcn_sched_barrier(0);

    // ---- compute own m-tile(s): NO cross-wave barrier on the x path ----
    f32x4 accA[4], accB[4];   // per n-tile; accB used by wave 3 only
#pragma unroll
    for (int n = 0; n < 4; ++n) { accA[n] = (f32x4){0.f,0.f,0.f,0.f}; accB[n] = (f32x4){0.f,0.f,0.f,0.f}; }

    const int rsw = lr & 7;
    auto compute_m = [&](int m, f32x4* acc) {
        const char* base = smem + m * 8192 + lr * 512;
#pragma unroll
        for (int kc = 0; kc < 4; ++kc) {
            const int u0 = kc * 8 + lk * 2;
            const f32x4 p0 = *reinterpret_cast<const f32x4*>(base + ((u0)     ^ rsw) * 16);
            const f32x4 p1 = *reinterpret_cast<const f32x4*>(base + ((u0 + 1) ^ rsw) * 16);
            union { unsigned u[4]; bf16x8 v; } af;
            af.u[0] = cvtpk(p0[0], p0[1]);
            af.u[1] = cvtpk(p0[2], p0[3]);
            af.u[2] = cvtpk(p1[0], p1[1]);
            af.u[3] = cvtpk(p1[2], p1[3]);
#pragma unroll
            for (int n = 0; n < 4; ++n)
                acc[n] = __builtin_amdgcn_mfma_f32_16x16x32_bf16(af.v, bfrag[n][kc], acc[n], 0, 0, 0);
        }
    };

    compute_m(w, accA);
    if (w == 3) {
        asm volatile("s_waitcnt vmcnt(0)" ::: "memory");   // m=4's loads landed
        __builtin_amdgcn_sched_barrier(0);
        compute_m(4, accB);
    }

    // ---- barrier #1: all waves done reading x -> safe to alias hw over it ----
    barrier_lds();

    // ---- acc -> hw f32 [80][68] (D-frag: row = m*16 + lk*4 + r, col = n*16 + lr) ----
    {
        float* hw = reinterpret_cast<float*>(smem);
#pragma unroll
        for (int n = 0; n < 4; ++n)
#pragma unroll
            for (int r = 0; r < 4; ++r)
                hw[(w * 16 + lk * 4 + r) * 68 + n * 16 + lr] = accA[n][r];
        if (w == 3) {
#pragma unroll
            for (int n = 0; n < 4; ++n)
#pragma unroll
                for (int r = 0; r < 4; ++r)
                    hw[(4 * 16 + lk * 4 + r) * 68 + n * 16 + lr] = accB[n][r];
        }
    }
    barrier_lds();

    // ---- online softmax over K=10 + leaky relu, thread = (node, head) ----
    if (t < NPB * Hc) {   // 128 active
        const int h  = t & 15;
        const int ln = t >> 4;
        const float ar0 = a[h];
        const float ar1 = a[16 + h];
        const float ar2 = a[32 + h];
        const float ar3 = a[48 + h];
        const float* hwb = reinterpret_cast<const float*>(smem) + (ln * Kc) * 68 + h * 4;

        float mx = -1e30f, lsum = 0.f;
        float o0 = 0.f, o1 = 0.f, o2 = 0.f, o3 = 0.f;
#pragma unroll
        for (int k = 0; k < Kc; ++k) {
            const float4 hv = *reinterpret_cast<const float4*>(hwb + k * 68);
            const float lg = fmaf(hv.x, ar0, fmaf(hv.y, ar1, fmaf(hv.z, ar2, hv.w * ar3)));
            const float mn = fmaxf(mx, lg);
            const float s  = __expf(mx - mn);
            const float p  = __expf(lg - mn);
            mx = mn;
            lsum = fmaf(lsum, s, p);
            o0 = fmaf(o0, s, p * hv.x);
            o1 = fmaf(o1, s, p * hv.y);
            o2 = fmaf(o2, s, p * hv.z);
            o3 = fmaf(o3, s, p * hv.w);
        }
        const float inv = 1.f / lsum;
        o0 *= inv; o1 *= inv; o2 *= inv; o3 *= inv;
        o0 = fmaxf(o0, 0.2f * o0);   // leaky_relu slope 0.2
        o1 = fmaxf(o1, 0.2f * o1);
        o2 = fmaxf(o2, 0.2f * o2);
        o3 = fmaxf(o3, 0.2f * o3);
        float* ol = reinterpret_cast<float*>(smem + OL_OFF);
        *reinterpret_cast<float4*>(ol + ln * 68 + h * 4) = make_float4(o0, o1, o2, o3);
    }
    barrier_lds();

    // ---- store transposed [B, 64, N], coalesced float4 ----
    if (t < 128) {
        const float* ol = reinterpret_cast<const float*>(smem + OL_OFF);
        const int c  = t >> 1;   // channel 0..63
        const int nq = t & 1;    // node quad 0..1
        const int nb = blockIdx.x * NPB;
        const int b  = nb / Nc;
        const int n0 = nb - b * Nc;
        float4 v;
        v.x = ol[(nq * 4 + 0) * 68 + c];
        v.y = ol[(nq * 4 + 1) * 68 + c];
        v.z = ol[(nq * 4 + 2) * 68 + c];
        v.w = ol[(nq * 4 + 3) * 68 + c];
        *reinterpret_cast<float4*>(out + ((size_t)b * Cc + c) * Nc + n0 + nq * 4) = v;
    }
}

extern "C" void kernel_launch(void* const* d_in, const int* in_sizes, int n_in,
                              void* d_out, int out_size, void* d_ws, size_t ws_size,
                              hipStream_t stream) {
    const float* x = (const float*)d_in[0];
    const float* W = (const float*)d_in[1];
    const float* a = (const float*)d_in[2];
    float* out = (float*)d_out;
    unsigned short* wt = (unsigned short*)d_ws;   // 16 KB used

    prep_w<<<32, 256, 0, stream>>>(W, wt);
    gat_kernel<<<NTILES, BLK, 0, stream>>>(x, wt, a, out);
}